// Round 15
// baseline (326.453 us; speedup 1.0000x reference)
//
#include <hip/hip_runtime.h>

#define NB 4
#define NC 512
#define ND 64
#define HW 4096
#define SPIN 6400

typedef _Float16 f16;
typedef _Float16 f16x8 __attribute__((ext_vector_type(8)));
typedef short s16x8 __attribute__((ext_vector_type(8)));
typedef short s16x4 __attribute__((ext_vector_type(4)));
typedef float f32x4 __attribute__((ext_vector_type(4)));
typedef float f32x16 __attribute__((ext_vector_type(16)));
typedef unsigned short ushortT;

__device__ __forceinline__ unsigned short f32_to_bf16(float x) {
  union { float f; unsigned u; } v; v.f = x;
  unsigned r = v.u + 0x7FFFu + ((v.u >> 16) & 1u);
  return (unsigned short)(r >> 16);
}

__device__ __forceinline__ void stv(float* p, float v) { *p = v; }
__device__ __forceinline__ void stv(f16* p, float v) { *p = (f16)v; }
__device__ __forceinline__ void stv(unsigned short* p, float v) { *p = f32_to_bf16(v); }

__device__ __forceinline__ unsigned cvt_pk_bf16(float lo, float hi) {
  unsigned r;
  asm("v_cvt_pk_bf16_f32 %0, %1, %2" : "=v"(r) : "v"(lo), "v"(hi));
  return r;
}

#if __has_builtin(__builtin_amdgcn_exp2f)
#define EXP2F(x) __builtin_amdgcn_exp2f(x)
#else
#define EXP2F(x) exp2f(x)
#endif

// lgkmcnt(0) (my ds_writes visible) + barrier, fused in one memory-clobbered asm so
// no LDS op can cross. vmcnt deliberately NOT drained: K/V prefetch loads stay in
// flight across the barrier; the compiler inserts counted vmcnt waits at reg use (T4).
#define BARRIER_NODRAIN() \
  asm volatile("s_waitcnt lgkmcnt(0)\n\ts_barrier" ::: "memory")

// ---------------- all weights f32 -> f16, one launch ----------------
__global__ __launch_bounds__(256) void cvtw_kernel(const float* __restrict__ fw,
                                                   const float* __restrict__ gw,
                                                   const float* __restrict__ hw,
                                                   const float* __restrict__ ow,
                                                   f16* __restrict__ dst) {
  int i = blockIdx.x * 256 + threadIdx.x;
  const float* src; int off;
  if (i < 32768) { src = fw; off = 0; }
  else if (i < 65536) { src = gw; off = 32768; }
  else if (i < 327680) { src = hw; off = 65536; }
  else { src = ow; off = 327680; }
  dst[i] = (f16)src[i - off];
}

// ---------------- transpose+cvt: f32 [b][512][4096] -> f16 [b][4096][512] ----------------
__global__ __launch_bounds__(256) void tcvt_kernel(const float* __restrict__ in,
                                                   f16* __restrict__ out) {
  __shared__ float Xs[64][65];
  int p0 = blockIdx.x * 64, c0 = blockIdx.y * 64, b = blockIdx.z;
  int t = threadIdx.x;
  const float* ib = in + ((size_t)b * NC + c0) * HW + p0;
  int pl = t & 63, cg = t >> 6;
#pragma unroll
  for (int k = 0; k < 16; ++k) {
    int c = cg * 16 + k;
    Xs[c][pl] = ib[(size_t)c * HW + pl];
  }
  __syncthreads();
  int p = t >> 2, cb = (t & 3) * 16;
  union { f16 h[16]; float4 q[2]; } u;
#pragma unroll
  for (int j = 0; j < 16; ++j) u.h[j] = (f16)Xs[cb + j][p];
  f16* ob = out + ((size_t)b * HW + p0 + p) * NC + c0 + cb;
  *(float4*)(ob) = u.q[0];
  *(float4*)(ob + 8) = u.q[1];
}

// ---------------- fused bilinear-resize(80->64) + transpose + cvt for style ----------------
__global__ __launch_bounds__(256) void rstcvt_kernel(const float* __restrict__ X,
                                                     f16* __restrict__ Y) {
  __shared__ float Xs[64 * 165];
  int oy = blockIdx.x, c0 = blockIdx.y * 64, b = blockIdx.z;
  float syf = fmaxf((oy + 0.5f) * 1.25f - 0.5f, 0.f);
  int y0 = (int)syf; int y1 = min(y0 + 1, 79); float wy = syf - (float)y0;
  int t = threadIdx.x;
  const float* Xb = X + ((size_t)b * NC + c0) * SPIN;
#pragma unroll
  for (int k = 0; k < 10; ++k) {
    int idx = t + k * 256;
    int c = idx / 40;
    int rem = idx - c * 40;
    int yy = rem / 20;
    int x4 = rem - yy * 20;
    int ysrc = yy ? y1 : y0;
    float4 v = *(const float4*)(Xb + (size_t)c * SPIN + ysrc * 80 + x4 * 4);
    float* d = Xs + c * 165 + yy * 82 + x4 * 4;
    d[0] = v.x; d[1] = v.y; d[2] = v.z; d[3] = v.w;
  }
  __syncthreads();
  int ox = t >> 2, cb = (t & 3) * 16;
  float sxf = fmaxf((ox + 0.5f) * 1.25f - 0.5f, 0.f);
  int x0 = (int)sxf; int x1 = min(x0 + 1, 79); float wx = sxf - (float)x0;
  union { f16 h[16]; float4 q[2]; } u;
#pragma unroll
  for (int j = 0; j < 16; ++j) {
    const float* base = Xs + (cb + j) * 165;
    float a0 = base[x0], a1 = base[x1];
    float b0 = base[82 + x0], b1 = base[82 + x1];
    float r0 = a0 + (a1 - a0) * wx;
    float r1 = b0 + (b1 - b0) * wx;
    u.h[j] = (f16)(r0 + (r1 - r0) * wy);
  }
  f16* ob = Y + ((size_t)b * HW + oy * 64 + ox) * NC + c0 + cb;
  *(float4*)(ob) = u.q[0];
  *(float4*)(ob + 8) = u.q[1];
}

// ---------------- f & g conv1x1 fused, position-major out (O=64) ----------------
__global__ __launch_bounds__(256) void convpm2_kernel(const f16* __restrict__ X0,
                                                      const f16* __restrict__ X1,
                                                      const f16* __restrict__ W01,
                                                      const float* __restrict__ b0,
                                                      const float* __restrict__ b1,
                                                      f16* __restrict__ Y0,
                                                      f16* __restrict__ Y1) {
  int sel = blockIdx.z >> 2;
  int b = blockIdx.z & 3;
  const f16* X = sel ? X1 : X0;
  const f16* W = W01 + sel * (ND * NC);
  const float* bias = sel ? b1 : b0;
  f16* Y = sel ? Y1 : Y0;
  int t = threadIdx.x, l = t & 63, w = t >> 6;
  int pw = blockIdx.x * 256 + w * 64;
  int l4 = l & 15, g = l >> 4;
  f32x4 acc[4][4] = {};
  const f16* Xb = X + ((size_t)b * HW + pw) * NC;
  for (int kk = 0; kk < 16; ++kk) {
    int co = kk * 32 + g * 8;
    f16x8 a[4], bb[4];
#pragma unroll
    for (int ms = 0; ms < 4; ++ms) a[ms] = *(const f16x8*)(Xb + (size_t)(ms * 16 + l4) * NC + co);
#pragma unroll
    for (int ct = 0; ct < 4; ++ct) bb[ct] = *(const f16x8*)(W + (size_t)(ct * 16 + l4) * NC + co);
#pragma unroll
    for (int ms = 0; ms < 4; ++ms)
#pragma unroll
      for (int ct = 0; ct < 4; ++ct)
        acc[ms][ct] = __builtin_amdgcn_mfma_f32_16x16x32_f16(a[ms], bb[ct], acc[ms][ct], 0, 0, 0);
  }
  float bv[4];
#pragma unroll
  for (int ct = 0; ct < 4; ++ct) bv[ct] = bias[ct * 16 + l4];
  f16* Yb = Y + ((size_t)b * HW + pw) * ND;
#pragma unroll
  for (int ms = 0; ms < 4; ++ms)
#pragma unroll
    for (int ct = 0; ct < 4; ++ct)
#pragma unroll
      for (int r = 0; r < 4; ++r)
        Yb[(size_t)(ms * 16 + g * 4 + r) * ND + ct * 16 + l4] = (f16)(acc[ms][ct][r] + bv[ct]);
}

// ---------------- conv1x1, channel-major out ----------------
template <typename OUT_T>
__global__ __launch_bounds__(256) void convcm_kernel(const f16* __restrict__ X,
                                                     const f16* __restrict__ W,
                                                     const float* __restrict__ bias,
                                                     OUT_T* __restrict__ Y, int O) {
  int b = blockIdx.z;
  int o0 = blockIdx.x * 64;
  int t = threadIdx.x, l = t & 63, w = t >> 6;
  int pw = blockIdx.y * 256 + w * 64;
  int l4 = l & 15, g = l >> 4;
  f32x4 acc[4][4] = {};
  const f16* Xb = X + ((size_t)b * HW + pw) * NC;
  const f16* Wb = W + (size_t)o0 * NC;
  for (int kk = 0; kk < 16; ++kk) {
    int co = kk * 32 + g * 8;
    f16x8 a[4], bb[4];
#pragma unroll
    for (int ms = 0; ms < 4; ++ms) a[ms] = *(const f16x8*)(Wb + (size_t)(ms * 16 + l4) * NC + co);
#pragma unroll
    for (int ct = 0; ct < 4; ++ct) bb[ct] = *(const f16x8*)(Xb + (size_t)(ct * 16 + l4) * NC + co);
#pragma unroll
    for (int ms = 0; ms < 4; ++ms)
#pragma unroll
      for (int ct = 0; ct < 4; ++ct)
        acc[ms][ct] = __builtin_amdgcn_mfma_f32_16x16x32_f16(a[ms], bb[ct], acc[ms][ct], 0, 0, 0);
  }
  float bv[4][4];
#pragma unroll
  for (int ms = 0; ms < 4; ++ms)
#pragma unroll
    for (int r = 0; r < 4; ++r) bv[ms][r] = bias[o0 + ms * 16 + g * 4 + r];
#pragma unroll
  for (int ms = 0; ms < 4; ++ms)
#pragma unroll
    for (int ct = 0; ct < 4; ++ct)
#pragma unroll
      for (int r = 0; r < 4; ++r) {
        float val = acc[ms][ct][r] + bv[ms][r];
        stv(&Y[((size_t)b * O + o0 + ms * 16 + g * 4 + r) * HW + pw + ct * 16 + l4], val);
      }
}

// ---------------- flash attention v12: v7 layout + no-drain barrier (T4) -------------
// FT,GT: f16 [b][4096][64]; HC: bf16 [b][512][4096]; MIDT: f16 [b][4096][512]
// grid 512 (2/CU): block = 64m x 256c, 4 waves = 2mf x 2cq; wave 32m x 128c; n-tile 64.
// Barrier = lgkmcnt(0)+s_barrier only (fused asm): K/V global prefetch stays in flight
// across the barrier; compiler inserts counted vmcnt at register use. Stage pattern =
// v7's verified layout (sc=t>>3). exp2 + log2e-prescaled Q; pointer-bumped addressing.
union PAu { unsigned u[4]; s16x8 v; };
union VSu { s16x8 v; s16x4 h[2]; };

__global__ __launch_bounds__(256, 2) void attn_kernel(const f16* __restrict__ FT,
                                                      const f16* __restrict__ GT,
                                                      const unsigned short* __restrict__ HC,
                                                      f16* __restrict__ MIDT) {
  __shared__ __align__(16) char Vs[2][32768];  // [buf][c-local 256][128B], sigma+XOR
  int bid = blockIdx.x;
  int b = (bid & 7) >> 1;   // batch -> XCD pair
  int cs = bid & 1;         // channel half
  int mt = bid >> 3;        // 0..63
  int t = threadIdx.x, l = t & 63, w = t >> 6;
  int lm = l & 31, hf = l >> 5;
  int mf = w >> 1, cq = w & 1;
  int mr = mt * 64 + mf * 32;
  int cqb = cq * 128;

  // Q B-frags, prescaled by log2(e): exp(S) = exp2(S')
  const f16* Fq = FT + ((size_t)b * HW + mr + lm) * ND + hf * 8;
  f16x8 q[4];
  {
    const f16 l2e = (f16)1.44269504f;
#pragma unroll
    for (int kc = 0; kc < 4; ++kc) {
      f16x8 v = *(const f16x8*)(Fq + kc * 16);
#pragma unroll
      for (int j = 0; j < 8; ++j) v[j] *= l2e;
      q[kc] = v;
    }
  }

  // K A-frag pointers (row n = lm, c-slot (hf,kc)); bumped 64 rows / iter
  const f16* kp0 = GT + (size_t)b * HW * ND + (size_t)lm * ND + hf * 8;
  const f16* kp1 = kp0 + 32 * ND;

  // V stage (v7 pattern): thread covers rows c = r*32 + sc (sc = t>>3), 8 n at (t&7)*8
  int sc = t >> 3;
  int nseg = (t & 7) * 8;
  int sb0 = ((nseg >> 4) * 32) + (((nseg >> 3) & 1) * 8);  // sigma'd byte offset
  int swv = (sc & 7) << 4;                                  // (cl&7)==(sc&7), r*32%8==0
  const unsigned short* vp = HC + ((size_t)b * NC + cs * 256 + sc) * HW + nseg;
  char* wa = Vs[0] + sc * 128 + (sb0 ^ swv);         // h[0] slots (+r*4096, +BOFF)
  char* wbp = Vs[0] + sc * 128 + ((sb0 + 16) ^ swv); // h[1] slots

  // PV read bases: row cl0+cf*32, frag kn at ((kn*32+hf*16)^vsw); cf,buf via imm
  int cl0 = cqb + lm;
  int vsw = (lm & 7) << 4;
  const char* r0 = Vs[0] + cl0 * 128 + ((0 + hf * 16) ^ vsw);
  const char* r1 = Vs[0] + cl0 * 128 + ((32 + hf * 16) ^ vsw);
  const char* r2 = Vs[0] + cl0 * 128 + ((64 + hf * 16) ^ vsw);
  const char* r3 = Vs[0] + cl0 * 128 + ((96 + hf * 16) ^ vsw);

  f32x16 acc[4] = {};
  float den = 0.f;

#define KLOAD(KN)                                                          \
  do {                                                                     \
    _Pragma("unroll") for (int kc = 0; kc < 4; ++kc) {                     \
      KN[0][kc] = *(const f16x8*)(kp0 + kc * 16);                          \
      KN[1][kc] = *(const f16x8*)(kp1 + kc * 16);                          \
    }                                                                      \
    kp0 += 64 * ND; kp1 += 64 * ND;                                        \
  } while (0)

#define VLOAD()                                                            \
  do {                                                                     \
    _Pragma("unroll") for (int r_ = 0; r_ < 8; ++r_)                       \
        vreg[r_].v = *(const s16x8*)(vp + (size_t)r_ * 32 * HW);           \
    vp += 64;                                                              \
  } while (0)

#define VWRITE(BOFF)                                                       \
  do {                                                                     \
    _Pragma("unroll") for (int r_ = 0; r_ < 8; ++r_) {                     \
      *(s16x4*)(wa + (BOFF) + r_ * 4096) = vreg[r_].h[0];                  \
      *(s16x4*)(wbp + (BOFF) + r_ * 4096) = vreg[r_].h[1];                 \
    }                                                                      \
  } while (0)

#define PACK(sv, PA, o)                                                    \
  do {                                                                     \
    float p_[16];                                                          \
    _Pragma("unroll") for (int r_ = 0; r_ < 16; ++r_) p_[r_] = EXP2F(sv[r_]); \
    float d0_ = (p_[0] + p_[1]) + (p_[2] + p_[3]);                         \
    float d1_ = (p_[4] + p_[5]) + (p_[6] + p_[7]);                         \
    float d2_ = (p_[8] + p_[9]) + (p_[10] + p_[11]);                       \
    float d3_ = (p_[12] + p_[13]) + (p_[14] + p_[15]);                     \
    den += (d0_ + d1_) + (d2_ + d3_);                                      \
    PA[o].u[0] = cvt_pk_bf16(p_[0], p_[1]);                                \
    PA[o].u[1] = cvt_pk_bf16(p_[2], p_[3]);                                \
    PA[o].u[2] = cvt_pk_bf16(p_[4], p_[5]);                                \
    PA[o].u[3] = cvt_pk_bf16(p_[6], p_[7]);                                \
    PA[o + 1].u[0] = cvt_pk_bf16(p_[8], p_[9]);                            \
    PA[o + 1].u[1] = cvt_pk_bf16(p_[10], p_[11]);                          \
    PA[o + 1].u[2] = cvt_pk_bf16(p_[12], p_[13]);                          \
    PA[o + 1].u[3] = cvt_pk_bf16(p_[14], p_[15]);                          \
  } while (0)

#define PVBODY(PA, BOFF)                                                   \
  do {                                                                     \
    _Pragma("unroll") for (int cf = 0; cf < 4; ++cf) {                     \
      s16x8 v0_ = *(const s16x8*)(r0 + (BOFF) + cf * 4096);                \
      s16x8 v1_ = *(const s16x8*)(r1 + (BOFF) + cf * 4096);                \
      s16x8 v2_ = *(const s16x8*)(r2 + (BOFF) + cf * 4096);                \
      s16x8 v3_ = *(const s16x8*)(r3 + (BOFF) + cf * 4096);                \
      __builtin_amdgcn_s_setprio(1);                                       \
      acc[cf] = __builtin_amdgcn_mfma_f32_32x32x16_bf16(PA[0].v, v0_, acc[cf], 0, 0, 0); \
      acc[cf] = __builtin_amdgcn_mfma_f32_32x32x16_bf16(PA[1].v, v1_, acc[cf], 0, 0, 0); \
      acc[cf] = __builtin_amdgcn_mfma_f32_32x32x16_bf16(PA[2].v, v2_, acc[cf], 0, 0, 0); \
      acc[cf] = __builtin_amdgcn_mfma_f32_32x32x16_bf16(PA[3].v, v3_, acc[cf], 0, 0, 0); \
      __builtin_amdgcn_s_setprio(0);                                       \
    }                                                                      \
  } while (0)

// ITER: pref K(it+1)->KN, V(it+1)->vreg | QK(it) on KC | PV(it-1) on PP | pack->PC
//       | lgkmcnt(0)+barrier (NO vmcnt drain) | VWRITE(it+1)
#define ITER(PC, PP, KC, KN, BOFF, PRE, DOPV)                              \
  do {                                                                     \
    VSu vreg[8];                                                           \
    if (PRE) { KLOAD(KN); VLOAD(); }                                       \
    f32x16 s0 = {}, s1 = {};                                               \
    __builtin_amdgcn_s_setprio(1);                                         \
    _Pragma("unroll") for (int kc = 0; kc < 4; ++kc)                       \
        s0 = __builtin_amdgcn_mfma_f32_32x32x16_f16(KC[0][kc], q[kc], s0, 0, 0, 0); \
    _Pragma("unroll") for (int kc = 0; kc < 4; ++kc)                       \
        s1 = __builtin_amdgcn_mfma_f32_32x32x16_f16(KC[1][kc], q[kc], s1, 0, 0, 0); \
    __builtin_amdgcn_s_setprio(0);                                         \
    if (DOPV) PVBODY(PP, BOFF);                                            \
    PACK(s0, PC, 0);                                                       \
    PACK(s1, PC, 2);                                                       \
    BARRIER_NODRAIN();                                                     \
    if (PRE) VWRITE(BOFF);                                                 \
  } while (0)

  // prologue: V tile0 -> buf0; K tile0 -> kbA
  {
    VSu vreg[8];
    VLOAD();
    VWRITE(0);
  }
  f16x8 kbA[2][4], kbB[2][4];
  KLOAD(kbA);
  BARRIER_NODRAIN();

  PAu paA[4], paB[4];
  // IT=0 (even): no PV; writes tile1 -> buf1
  ITER(paA, paB, kbA, kbB, 32768, true, false);
  for (int ito = 0; ito < 31; ++ito) {
    // IT odd: PV(prev even tile, buf0); writes buf0
    ITER(paB, paA, kbB, kbA, 0, true, true);
    // IT even: PV(prev odd tile, buf1); writes buf1 (last: IT=62 writes tile63->buf1)
    ITER(paA, paB, kbA, kbB, 32768, true, true);
  }
  // IT=63 (odd): PV(tile62, buf0); no prefetch/write
  ITER(paB, paA, kbB, kbA, 0, false, true);
  // epilogue: PV(tile63) from buf1
  PVBODY(paB, 32768);

#undef KLOAD
#undef VLOAD
#undef VWRITE
#undef PACK
#undef PVBODY
#undef ITER

  // den: lane (lm,hf) holds its slot-half's sum for m = mr+lm; xor32 completes
  den += __shfl_xor(den, 32);
  float rd = 1.f / den;
  f16* Mb = MIDT + ((size_t)b * HW + mr) * NC + cs * 256 + cqb + lm;
#pragma unroll
  for (int r = 0; r < 16; ++r) {
    int mrow = (r & 3) + 8 * (r >> 2) + 4 * hf;
    float rv = __shfl(rd, mrow);
#pragma unroll
    for (int cf = 0; cf < 4; ++cf)
      Mb[(size_t)mrow * NC + cf * 32] = (f16)(acc[cf][r] * rv);
  }
}

extern "C" void kernel_launch(void* const* d_in, const int* in_sizes, int n_in,
                              void* d_out, int out_size, void* d_ws, size_t ws_size,
                              hipStream_t stream) {
  const float* content = (const float*)d_in[0];
  const float* style   = (const float*)d_in[1];
  const float* f_w = (const float*)d_in[2];
  const float* f_b = (const float*)d_in[3];
  const float* g_w = (const float*)d_in[4];
  const float* g_b = (const float*)d_in[5];
  const float* h_w = (const float*)d_in[6];
  const float* h_b = (const float*)d_in[7];
  const float* out_w = (const float*)d_in[8];
  const float* out_b = (const float*)d_in[9];
  float* out = (float*)d_out;

  const size_t MB = 1ull << 20;
  char* base = (char*)d_ws;
  f16* contentT = (f16*)base;            // [0,16M) dead after f-conv
  f16* midT     = (f16*)base;            // reuse
  unsigned short* hC = (unsigned short*)(base + 16 * MB);  // [16,32M)
  f16* fT = (f16*)(base + 32 * MB);
  f16* gT = (f16*)(base + 34 * MB);
  f16* styrT = (f16*)(base + 48 * MB);   // [48,64M)
  f16* w16 = (f16*)(base + 64 * MB);
  f16* fw16 = w16;
  f16* gw16 = w16 + 32768;
  f16* hw16 = w16 + 65536;
  f16* ow16 = w16 + 327680;

  cvtw_kernel<<<dim3(589824 / 256), 256, 0, stream>>>(f_w, g_w, h_w, out_w, w16);
  tcvt_kernel<<<dim3(HW / 64, NC / 64, NB), 256, 0, stream>>>(content, contentT);
  rstcvt_kernel<<<dim3(64, NC / 64, NB), 256, 0, stream>>>(style, styrT);
  convpm2_kernel<<<dim3(HW / 256, 1, 2 * NB), 256, 0, stream>>>(contentT, styrT, fw16, f_b, g_b, fT, gT);
  convcm_kernel<unsigned short><<<dim3(NC / 64, HW / 256, NB), 256, 0, stream>>>(styrT, hw16, h_b, hC, NC);
  attn_kernel<<<dim3(512), 256, 0, stream>>>(fT, gT, hC, midT);
  convcm_kernel<float><<<dim3(NC / 64, HW / 256, NB), 256, 0, stream>>>(midT, ow16, out_b, out, NC);
}

// Round 16
// 267.716 us; speedup vs baseline: 1.2194x; 1.2194x over previous
//
#include <hip/hip_runtime.h>

#define NB 4
#define NC 512
#define ND 64
#define HW 4096
#define SPIN 6400

typedef _Float16 f16;
typedef _Float16 f16x8 __attribute__((ext_vector_type(8)));
typedef short s16x8 __attribute__((ext_vector_type(8)));
typedef short s16x4 __attribute__((ext_vector_type(4)));
typedef float f32x4 __attribute__((ext_vector_type(4)));
typedef float f32x16 __attribute__((ext_vector_type(16)));
typedef unsigned short ushortT;

__device__ __forceinline__ unsigned short f32_to_bf16(float x) {
  union { float f; unsigned u; } v; v.f = x;
  unsigned r = v.u + 0x7FFFu + ((v.u >> 16) & 1u);
  return (unsigned short)(r >> 16);
}

__device__ __forceinline__ void stv(float* p, float v) { *p = v; }
__device__ __forceinline__ void stv(f16* p, float v) { *p = (f16)v; }
__device__ __forceinline__ void stv(unsigned short* p, float v) { *p = f32_to_bf16(v); }

__device__ __forceinline__ unsigned cvt_pk_bf16(float lo, float hi) {
  unsigned r;
  asm("v_cvt_pk_bf16_f32 %0, %1, %2" : "=v"(r) : "v"(lo), "v"(hi));
  return r;
}

// ---------------- all weights f32 -> f16, one launch ----------------
__global__ __launch_bounds__(256) void cvtw_kernel(const float* __restrict__ fw,
                                                   const float* __restrict__ gw,
                                                   const float* __restrict__ hw,
                                                   const float* __restrict__ ow,
                                                   f16* __restrict__ dst) {
  int i = blockIdx.x * 256 + threadIdx.x;
  const float* src; int off;
  if (i < 32768) { src = fw; off = 0; }
  else if (i < 65536) { src = gw; off = 32768; }
  else if (i < 327680) { src = hw; off = 65536; }
  else { src = ow; off = 327680; }
  dst[i] = (f16)src[i - off];
}

// ---------------- transpose+cvt: f32 [b][512][4096] -> f16 [b][4096][512] ----------------
__global__ __launch_bounds__(256) void tcvt_kernel(const float* __restrict__ in,
                                                   f16* __restrict__ out) {
  __shared__ float Xs[64][65];
  int p0 = blockIdx.x * 64, c0 = blockIdx.y * 64, b = blockIdx.z;
  int t = threadIdx.x;
  const float* ib = in + ((size_t)b * NC + c0) * HW + p0;
  int pl = t & 63, cg = t >> 6;
#pragma unroll
  for (int k = 0; k < 16; ++k) {
    int c = cg * 16 + k;
    Xs[c][pl] = ib[(size_t)c * HW + pl];
  }
  __syncthreads();
  int p = t >> 2, cb = (t & 3) * 16;
  union { f16 h[16]; float4 q[2]; } u;
#pragma unroll
  for (int j = 0; j < 16; ++j) u.h[j] = (f16)Xs[cb + j][p];
  f16* ob = out + ((size_t)b * HW + p0 + p) * NC + c0 + cb;
  *(float4*)(ob) = u.q[0];
  *(float4*)(ob + 8) = u.q[1];
}

// ---------------- fused bilinear-resize(80->64) + transpose + cvt for style ----------------
__global__ __launch_bounds__(256) void rstcvt_kernel(const float* __restrict__ X,
                                                     f16* __restrict__ Y) {
  __shared__ float Xs[64 * 165];
  int oy = blockIdx.x, c0 = blockIdx.y * 64, b = blockIdx.z;
  float syf = fmaxf((oy + 0.5f) * 1.25f - 0.5f, 0.f);
  int y0 = (int)syf; int y1 = min(y0 + 1, 79); float wy = syf - (float)y0;
  int t = threadIdx.x;
  const float* Xb = X + ((size_t)b * NC + c0) * SPIN;
#pragma unroll
  for (int k = 0; k < 10; ++k) {
    int idx = t + k * 256;
    int c = idx / 40;
    int rem = idx - c * 40;
    int yy = rem / 20;
    int x4 = rem - yy * 20;
    int ysrc = yy ? y1 : y0;
    float4 v = *(const float4*)(Xb + (size_t)c * SPIN + ysrc * 80 + x4 * 4);
    float* d = Xs + c * 165 + yy * 82 + x4 * 4;
    d[0] = v.x; d[1] = v.y; d[2] = v.z; d[3] = v.w;
  }
  __syncthreads();
  int ox = t >> 2, cb = (t & 3) * 16;
  float sxf = fmaxf((ox + 0.5f) * 1.25f - 0.5f, 0.f);
  int x0 = (int)sxf; int x1 = min(x0 + 1, 79); float wx = sxf - (float)x0;
  union { f16 h[16]; float4 q[2]; } u;
#pragma unroll
  for (int j = 0; j < 16; ++j) {
    const float* base = Xs + (cb + j) * 165;
    float a0 = base[x0], a1 = base[x1];
    float b0 = base[82 + x0], b1 = base[82 + x1];
    float r0 = a0 + (a1 - a0) * wx;
    float r1 = b0 + (b1 - b0) * wx;
    u.h[j] = (f16)(r0 + (r1 - r0) * wy);
  }
  f16* ob = Y + ((size_t)b * HW + oy * 64 + ox) * NC + c0 + cb;
  *(float4*)(ob) = u.q[0];
  *(float4*)(ob + 8) = u.q[1];
}

// ---------------- f & g conv1x1 fused, position-major out (O=64) ----------------
__global__ __launch_bounds__(256) void convpm2_kernel(const f16* __restrict__ X0,
                                                      const f16* __restrict__ X1,
                                                      const f16* __restrict__ W01,
                                                      const float* __restrict__ b0,
                                                      const float* __restrict__ b1,
                                                      f16* __restrict__ Y0,
                                                      f16* __restrict__ Y1) {
  int sel = blockIdx.z >> 2;
  int b = blockIdx.z & 3;
  const f16* X = sel ? X1 : X0;
  const f16* W = W01 + sel * (ND * NC);
  const float* bias = sel ? b1 : b0;
  f16* Y = sel ? Y1 : Y0;
  int t = threadIdx.x, l = t & 63, w = t >> 6;
  int pw = blockIdx.x * 256 + w * 64;
  int l4 = l & 15, g = l >> 4;
  f32x4 acc[4][4] = {};
  const f16* Xb = X + ((size_t)b * HW + pw) * NC;
  for (int kk = 0; kk < 16; ++kk) {
    int co = kk * 32 + g * 8;
    f16x8 a[4], bb[4];
#pragma unroll
    for (int ms = 0; ms < 4; ++ms) a[ms] = *(const f16x8*)(Xb + (size_t)(ms * 16 + l4) * NC + co);
#pragma unroll
    for (int ct = 0; ct < 4; ++ct) bb[ct] = *(const f16x8*)(W + (size_t)(ct * 16 + l4) * NC + co);
#pragma unroll
    for (int ms = 0; ms < 4; ++ms)
#pragma unroll
      for (int ct = 0; ct < 4; ++ct)
        acc[ms][ct] = __builtin_amdgcn_mfma_f32_16x16x32_f16(a[ms], bb[ct], acc[ms][ct], 0, 0, 0);
  }
  float bv[4];
#pragma unroll
  for (int ct = 0; ct < 4; ++ct) bv[ct] = bias[ct * 16 + l4];
  f16* Yb = Y + ((size_t)b * HW + pw) * ND;
#pragma unroll
  for (int ms = 0; ms < 4; ++ms)
#pragma unroll
    for (int ct = 0; ct < 4; ++ct)
#pragma unroll
      for (int r = 0; r < 4; ++r)
        Yb[(size_t)(ms * 16 + g * 4 + r) * ND + ct * 16 + l4] = (f16)(acc[ms][ct][r] + bv[ct]);
}

// ---------------- conv1x1 v2, channel-major out: LDS-staged X (BK=64 dbuf) -----------
// X tile 256p x 64c staged coalesced to LDS (XOR-swizzled rows); B-frags become
// conflict-free(2-way) ds_read_b128 instead of 16-cache-line global gathers.
template <typename OUT_T>
__global__ __launch_bounds__(256, 2) void convcm_kernel(const f16* __restrict__ X,
                                                        const f16* __restrict__ W,
                                                        const float* __restrict__ bias,
                                                        OUT_T* __restrict__ Y, int O) {
  __shared__ __align__(16) char Xs[2][32768];  // [buf][p 256][128B = 64 f16]
  int b = blockIdx.z;
  int o0 = blockIdx.x * 64;
  int t = threadIdx.x, l = t & 63, w = t >> 6;
  int pw0 = blockIdx.y * 256;
  int pw = pw0 + w * 64;
  int l4 = l & 15, g = l >> 4;
  f32x4 acc[4][4] = {};
  const f16* Xb = X + ((size_t)b * HW + pw0) * NC;
  const f16* Wb = W + (size_t)o0 * NC;

  // staging coords: thread covers rows p = r*32 + ps (r = 0..7), 16B slot ccs
  int ps = t >> 3, ccs = t & 7;
  const f16* xsrc = Xb + (size_t)ps * NC + ccs * 8;
  char* xw = Xs[0] + ps * 128 + ((ccs * 16) ^ ((ps & 7) << 4));  // +r*4096, +buf*32768

  // B-frag read: row = w*64 + ct*16 + l4; (row&7) == (l4&7) so swizzle is invariant
  const int rsw = (l4 & 7) << 4;
  const char* xrd = Xs[0] + (w * 64 + l4) * 128;  // + ct*2048 + ((kk2*64+g*16)^rsw) + buf

  for (int cn = 0; cn < 8; ++cn) {
    const int boff = (cn & 1) * 32768;
    // stage chunk cn (c = cn*64 .. +64) -> buf cn&1, in two 4-row batches (VGPR cap)
#pragma unroll
    for (int h = 0; h < 2; ++h) {
      s16x8 xreg[4];
#pragma unroll
      for (int r = 0; r < 4; ++r)
        xreg[r] = *(const s16x8*)(xsrc + (size_t)((h * 4 + r) * 32) * NC + cn * 64);
#pragma unroll
      for (int r = 0; r < 4; ++r)
        *(s16x8*)(xw + boff + (h * 4 + r) * 4096) = xreg[r];
    }
    __syncthreads();  // tile staged
    // compute chunk cn: W from global (L1-hot), X B-frags from LDS
#pragma unroll
    for (int kk2 = 0; kk2 < 2; ++kk2) {
      int co = cn * 64 + kk2 * 32 + g * 8;
      f16x8 a[4], bb[4];
#pragma unroll
      for (int ms = 0; ms < 4; ++ms)
        a[ms] = *(const f16x8*)(Wb + (size_t)(ms * 16 + l4) * NC + co);
#pragma unroll
      for (int ct = 0; ct < 4; ++ct)
        bb[ct] = *(const f16x8*)(xrd + boff + ct * 2048 + ((kk2 * 64 + g * 16) ^ rsw));
#pragma unroll
      for (int ms = 0; ms < 4; ++ms)
#pragma unroll
        for (int ct = 0; ct < 4; ++ct)
          acc[ms][ct] = __builtin_amdgcn_mfma_f32_16x16x32_f16(a[ms], bb[ct], acc[ms][ct], 0, 0, 0);
    }
    __syncthreads();  // reads done before buf reuse (cn+2)
  }

  float bv[4][4];
#pragma unroll
  for (int ms = 0; ms < 4; ++ms)
#pragma unroll
    for (int r = 0; r < 4; ++r) bv[ms][r] = bias[o0 + ms * 16 + g * 4 + r];
#pragma unroll
  for (int ms = 0; ms < 4; ++ms)
#pragma unroll
    for (int ct = 0; ct < 4; ++ct)
#pragma unroll
      for (int r = 0; r < 4; ++r) {
        float val = acc[ms][ct][r] + bv[ms][r];
        stv(&Y[((size_t)b * O + o0 + ms * 16 + g * 4 + r) * HW + pw + ct * 16 + l4], val);
      }
}

// ---------------- flash attention v7 (round-10 verified, 178us): PV lags QK ----------
// FT,GT: f16 [b][4096][64]; HC: bf16 [b][512][4096]; MIDT: f16 [b][4096][512]
// grid 512 (2/CU): block = 64m x 256c, 4 waves = 2mf x 2cq; wave 32m x 128c.
// Per iter: [stage_load(it+1) | K(it+1) | QK(it) | PV(it-1) | exp/pack(it)] BARRIER
// [stage_write(it+1)].  Single mid-iter barrier; happens-before verified.
union PAu { unsigned u[4]; s16x8 v; };
union VSu { s16x8 v; s16x4 h[2]; };

__global__ __launch_bounds__(256, 2) void attn_kernel(const f16* __restrict__ FT,
                                                      const f16* __restrict__ GT,
                                                      const unsigned short* __restrict__ HC,
                                                      f16* __restrict__ MIDT) {
  __shared__ __align__(16) char Vs[2][32768];  // [buf][c-local 256][128B]
  int bid = blockIdx.x;
  int b = (bid & 7) >> 1;   // batch -> XCD pair
  int cs = bid & 1;         // channel half
  int mt = bid >> 3;        // 0..63
  int t = threadIdx.x, l = t & 63, w = t >> 6;
  int lm = l & 31, hf = l >> 5;
  int mf = w >> 1, cq = w & 1;
  int mr = mt * 64 + mf * 32;
  int cqb = cq * 128;

  // Q B-frags: col = m = mr+lm, slot (hf,j) -> c = kc*16 + hf*8 + j
  const f16* Fq = FT + ((size_t)b * HW + mr + lm) * ND + hf * 8;
  f16x8 q[4];
#pragma unroll
  for (int kc = 0; kc < 4; ++kc) q[kc] = *(const f16x8*)(Fq + kc * 16);

  // K A-frags direct from global: row = n, slot (hf,j) -> c = kc*16+hf*8+j
  const f16* kp = GT + (size_t)b * HW * ND + (size_t)lm * ND + hf * 8;

  // V staging coords: thread stages rows cl = r*32+sc, 16B at n-seg nseg
  int sc = t >> 3;
  int nseg = (t & 7) * 8;
  int sb0 = ((nseg >> 4) * 32) + (((nseg >> 3) & 1) * 8);  // sigma'd byte offset
  const unsigned short* vsrc =
      HC + ((size_t)b * NC + cs * 256 + sc) * HW + nseg;

  f32x16 acc[4] = {};
  float den = 0.f;

  const int cl0 = cqb + lm;
  const int vsw = (lm & 7) << 4;

#define STAGE_LOAD(n0x)                                                   \
  do {                                                                    \
    _Pragma("unroll") for (int r_ = 0; r_ < 8; ++r_)                      \
        vreg[r_].v = *(const s16x8*)(vsrc + (size_t)r_ * 32 * HW + (n0x)); \
  } while (0)

#define STAGE_WRITE(bufidx)                                               \
  do {                                                                    \
    _Pragma("unroll") for (int r_ = 0; r_ < 8; ++r_) {                    \
      int cl_ = r_ * 32 + sc;                                             \
      char* row_ = Vs[bufidx] + cl_ * 128;                                \
      int sw_ = (cl_ & 7) << 4;                                           \
      *(s16x4*)(row_ + (sb0 ^ sw_)) = vreg[r_].h[0];                      \
      *(s16x4*)(row_ + ((sb0 + 16) ^ sw_)) = vreg[r_].h[1];               \
    }                                                                     \
  } while (0)

#define PACK(sv, PA, o)                                                   \
  do {                                                                    \
    float p_[16];                                                         \
    _Pragma("unroll") for (int r_ = 0; r_ < 16; ++r_) {                   \
      p_[r_] = __expf(sv[r_]);                                            \
      den += p_[r_];                                                      \
    }                                                                     \
    PA[o].u[0] = cvt_pk_bf16(p_[0], p_[1]);                               \
    PA[o].u[1] = cvt_pk_bf16(p_[2], p_[3]);                               \
    PA[o].u[2] = cvt_pk_bf16(p_[4], p_[5]);                               \
    PA[o].u[3] = cvt_pk_bf16(p_[6], p_[7]);                               \
    PA[o + 1].u[0] = cvt_pk_bf16(p_[8], p_[9]);                           \
    PA[o + 1].u[1] = cvt_pk_bf16(p_[10], p_[11]);                         \
    PA[o + 1].u[2] = cvt_pk_bf16(p_[12], p_[13]);                         \
    PA[o + 1].u[3] = cvt_pk_bf16(p_[14], p_[15]);                         \
  } while (0)

#define PVBODY(PA, Vc)                                                    \
  do {                                                                    \
    s16x8 vb_[4], vn_[4];                                                 \
    _Pragma("unroll") for (int kn = 0; kn < 4; ++kn)                      \
        vb_[kn] = *(const s16x8*)((Vc) + cl0 * 128 + ((kn * 32 + hf * 16) ^ vsw)); \
    _Pragma("unroll") for (int cf = 0; cf < 4; ++cf) {                    \
      if (cf < 3) {                                                       \
        const char* vr_ = (Vc) + (cl0 + (cf + 1) * 32) * 128;             \
        _Pragma("unroll") for (int kn = 0; kn < 4; ++kn)                  \
            vn_[kn] = *(const s16x8*)(vr_ + ((kn * 32 + hf * 16) ^ vsw)); \
      }                                                                   \
      __builtin_amdgcn_s_setprio(1);                                      \
      _Pragma("unroll") for (int kn = 0; kn < 4; ++kn)                    \
          acc[cf] = __builtin_amdgcn_mfma_f32_32x32x16_bf16(PA[kn].v, vb_[kn], acc[cf], 0, 0, 0); \
      __builtin_amdgcn_s_setprio(0);                                      \
      if (cf < 3) {                                                       \
        _Pragma("unroll") for (int kn = 0; kn < 4; ++kn) vb_[kn] = vn_[kn]; \
      }                                                                   \
    }                                                                     \
  } while (0)

// One pipelined iteration: QK(IT) into PC; PV(IT-1) from PP (skipped if !DOPV);
// K for tile IT in KC; loads K(IT+1) into KN.
#define ITER(IT, PC, PP, KC, KN, DOPV)                                    \
  do {                                                                    \
    const int n0 = (IT) * 64;                                             \
    VSu vreg[8];                                                          \
    if ((IT) < 63) {                                                      \
      STAGE_LOAD(n0 + 64);                                                \
      _Pragma("unroll") for (int h_ = 0; h_ < 2; ++h_)                    \
          _Pragma("unroll") for (int kc = 0; kc < 4; ++kc)                \
          KN[h_][kc] = *(const f16x8*)(kp + (size_t)(n0 + 64 + h_ * 32) * ND + kc * 16); \
    }                                                                     \
    f32x16 s0 = {}, s1 = {};                                              \
    _Pragma("unroll") for (int kc = 0; kc < 4; ++kc)                      \
        s0 = __builtin_amdgcn_mfma_f32_32x32x16_f16(KC[0][kc], q[kc], s0, 0, 0, 0); \
    _Pragma("unroll") for (int kc = 0; kc < 4; ++kc)                      \
        s1 = __builtin_amdgcn_mfma_f32_32x32x16_f16(KC[1][kc], q[kc], s1, 0, 0, 0); \
    if (DOPV) {                                                           \
      const char* Vc_ = Vs[((IT) + 1) & 1]; /* == (IT-1)&1 */             \
      PVBODY(PP, Vc_);                                                    \
    }                                                                     \
    PACK(s0, PC, 0);                                                      \
    PACK(s1, PC, 2);                                                      \
    __syncthreads();                                                      \
    if ((IT) < 63) STAGE_WRITE(((IT) + 1) & 1);                           \
  } while (0)

  // prologue: stage V tile 0 -> buf0; K tile 0 -> kbP
  {
    VSu vreg[8];
    STAGE_LOAD(0);
    STAGE_WRITE(0);
  }
  f16x8 kbP[2][4], kbQ[2][4];
#pragma unroll
  for (int h = 0; h < 2; ++h)
#pragma unroll
    for (int kc = 0; kc < 4; ++kc)
      kbP[h][kc] = *(const f16x8*)(kp + (size_t)(h * 32) * ND + kc * 16);
  __syncthreads();

  PAu paA[4], paB[4];
  ITER(0, paA, paB, kbP, kbQ, false);
  for (int ito = 1; ito < 63; ito += 2) {
    ITER(ito, paB, paA, kbQ, kbP, true);
    ITER(ito + 1, paA, paB, kbP, kbQ, true);
  }
  ITER(63, paB, paA, kbQ, kbP, true);
  // epilogue: PV for tile 63 (in buf 1, pa = paB)
  PVBODY(paB, (const char*)Vs[1]);

#undef STAGE_LOAD
#undef STAGE_WRITE
#undef PACK
#undef PVBODY
#undef ITER

  // den: lane (lm,hf) holds its slot-half's sum for m = mr+lm
  den += __shfl_xor(den, 32);
  float rd = 1.f / den;
  f16* Mb = MIDT + ((size_t)b * HW + mr) * NC + cs * 256 + cqb + lm;
#pragma unroll
  for (int r = 0; r < 16; ++r) {
    int mrow = (r & 3) + 8 * (r >> 2) + 4 * hf;
    float rv = __shfl(rd, mrow);
#pragma unroll
    for (int cf = 0; cf < 4; ++cf)
      Mb[(size_t)mrow * NC + cf * 32] = (f16)(acc[cf][r] * rv);
  }
}

extern "C" void kernel_launch(void* const* d_in, const int* in_sizes, int n_in,
                              void* d_out, int out_size, void* d_ws, size_t ws_size,
                              hipStream_t stream) {
  const float* content = (const float*)d_in[0];
  const float* style   = (const float*)d_in[1];
  const float* f_w = (const float*)d_in[2];
  const float* f_b = (const float*)d_in[3];
  const float* g_w = (const float*)d_in[4];
  const float* g_b = (const float*)d_in[5];
  const float* h_w = (const float*)d_in[6];
  const float* h_b = (const float*)d_in[7];
  const float* out_w = (const float*)d_in[8];
  const float* out_b = (const float*)d_in[9];
  float* out = (float*)d_out;

  const size_t MB = 1ull << 20;
  char* base = (char*)d_ws;
  f16* contentT = (f16*)base;            // [0,16M) dead after f-conv
  f16* midT     = (f16*)base;            // reuse
  unsigned short* hC = (unsigned short*)(base + 16 * MB);  // [16,32M)
  f16* fT = (f16*)(base + 32 * MB);
  f16* gT = (f16*)(base + 34 * MB);
  f16* styrT = (f16*)(base + 48 * MB);   // [48,64M)
  f16* w16 = (f16*)(base + 64 * MB);
  f16* fw16 = w16;
  f16* gw16 = w16 + 32768;
  f16* hw16 = w16 + 65536;
  f16* ow16 = w16 + 327680;

  cvtw_kernel<<<dim3(589824 / 256), 256, 0, stream>>>(f_w, g_w, h_w, out_w, w16);
  tcvt_kernel<<<dim3(HW / 64, NC / 64, NB), 256, 0, stream>>>(content, contentT);
  rstcvt_kernel<<<dim3(64, NC / 64, NB), 256, 0, stream>>>(style, styrT);
  convpm2_kernel<<<dim3(HW / 256, 1, 2 * NB), 256, 0, stream>>>(contentT, styrT, fw16, f_b, g_b, fT, gT);
  convcm_kernel<unsigned short><<<dim3(NC / 64, HW / 256, NB), 256, 0, stream>>>(styrT, hw16, h_b, hC, NC);
  attn_kernel<<<dim3(512), 256, 0, stream>>>(fT, gT, hC, midT);
  convcm_kernel<float><<<dim3(NC / 64, HW / 256, NB), 256, 0, stream>>>(midT, ow16, out_b, out, NC);
}